// Round 17
// baseline (373.532 us; speedup 1.0000x reference)
//
#include <hip/hip_runtime.h>
#include <math.h>

#define NN 8192
#define FF 128
#define MAXD 128
#define JQ 1024      // columns per j-window
#define NW 8         // number of j-windows
#define SUB 128      // s rows staged per subtile (kT3)

// ---------------- workspace layout (float offsets) ----------------
static constexpr int OFF_DEG  = 0;          // 8192
static constexpr int OFF_AGG  = 8192;       // 16384: agg0[8192], agg1[8192]
static constexpr int OFF_C1   = 24576;      // 16384  x_pool = s^T x1
static constexpr int OFF_C2   = 40960;      // 16384  adj_p  = s^T t
static constexpr int OFF_G    = 57344;      // 16384  G = s^T s
static constexpr int OFF_SCAL = 73728;      // 16
static constexpr int OFF_RCNT = 73744;      // 8192 (int)  [fallback only]
static constexpr int ZN       = 81936;
// non-zeroed:
static constexpr int OFF_X1   = 81936;      // 8192*128
static constexpr int OFF_S    = 1130512;    // 8192*128
static constexpr int OFF_T    = 2179088;    // main: BITMAP (8 MB spans T+EIDX); fallback: t
static constexpr int OFF_EIDX = 3227664;    // fallback: eidx
static constexpr int OFF_A3   = 4276240;    // 16384
static constexpr int OFF_PART = 4292624;    // tpart (8x1M; also kSF2 degp 256x24576) ++ cpart (3x1M)
static constexpr int CPART_OFF = 8388608;   // cpart offset within part
static constexpr size_t NEED_PART_BYTES =
    (size_t)(OFF_PART + CPART_OFF + 3*1048576) * 4;

__global__ __launch_bounds__(256) void k0_zero(float* __restrict__ p, int n) {
    int i = blockIdx.x * 256 + threadIdx.x;
    if (i < n) p[i] = 0.0f;
}

// ---- Fused coalesced scan + deg/agg LDS histogram + ballot bitmap. ----
// block = (32-row strip) x (2048-col quarter); 1024 blocks; 24KB LDS.
// Per instruction: 256 threads read 4KB CONTIGUOUS (lane stride 16B).
// Bitmap word[row*128 + chunk*4 + q], chunk = q4*8 + seg*4 + wv,
// bit l <-> col chunk*256 + l*4 + q  (same layout kT3 expects).
__global__ __launch_bounds__(256) void kSF2(
    const float* __restrict__ A, const float* __restrict__ nodes,
    unsigned long long* __restrict__ bmp, float* __restrict__ degp,
    float* __restrict__ scal) {
    if (blockIdx.x == 0 && threadIdx.x < 16) scal[threadIdx.x] = 0.0f;
    __shared__ float hd[2048], h0[2048], h1[2048];   // 24 KB
    const int strip = blockIdx.x >> 2;   // 0..255 (32 rows each)
    const int q4    = blockIdx.x & 3;    // 0..3  (2048 cols each)
    const int tid   = threadIdx.x;
    const int lane  = tid & 63;
    const int wv    = tid >> 6;          // wave 0..3
    for (int i = tid; i < 2048; i += 256) { hd[i] = 0.0f; h0[i] = 0.0f; h1[i] = 0.0f; }
    __syncthreads();
    const int qlo = q4 << 11;
    for (int r = 0; r < 32; ++r) {
        const int row = (strip << 5) + r;
        const float n0 = nodes[2*row], n1 = nodes[2*row+1];
        #pragma unroll
        for (int seg = 0; seg < 2; ++seg) {
            const float4 v = *reinterpret_cast<const float4*>(
                A + (size_t)row * NN + qlo + (seg << 10) + (tid << 2));
            const unsigned long long m0 = __ballot(v.x != 0.0f);
            const unsigned long long m1 = __ballot(v.y != 0.0f);
            const unsigned long long m2 = __ballot(v.z != 0.0f);
            const unsigned long long m3 = __ballot(v.w != 0.0f);
            if (lane == 0) {
                const int chunk = (q4 << 3) + (seg << 2) + wv;
                unsigned long long* wp = bmp + ((size_t)row << 7) + (chunk << 2);
                wp[0] = m0; wp[1] = m1; wp[2] = m2; wp[3] = m3;
            }
            const int rel = (seg << 10) + (tid << 2);
            if (v.x != 0.0f) { atomicAdd(&hd[rel+0],1.0f); atomicAdd(&h0[rel+0],n0); atomicAdd(&h1[rel+0],n1); }
            if (v.y != 0.0f) { atomicAdd(&hd[rel+1],1.0f); atomicAdd(&h0[rel+1],n0); atomicAdd(&h1[rel+1],n1); }
            if (v.z != 0.0f) { atomicAdd(&hd[rel+2],1.0f); atomicAdd(&h0[rel+2],n0); atomicAdd(&h1[rel+2],n1); }
            if (v.w != 0.0f) { atomicAdd(&hd[rel+3],1.0f); atomicAdd(&h0[rel+3],n0); atomicAdd(&h1[rel+3],n1); }
        }
    }
    __syncthreads();
    float* __restrict__ dstp = degp + (size_t)strip * 24576 + qlo;
    for (int i = tid; i < 2048; i += 256) {
        dstp[i]         = hd[i];
        dstp[8192 + i]  = h0[i];
        dstp[16384 + i] = h1[i];
    }
}

// reduce 256 strip-partials -> deg, agg0, agg1 ; nnz = sum(deg) -> scal[0]
__global__ __launch_bounds__(256) void kB2r(
    const float* __restrict__ degp, float* __restrict__ deg,
    float* __restrict__ agg0, float* __restrict__ agg1,
    float* __restrict__ scal) {
    __shared__ float red[256];
    const int tid = threadIdx.x;
    const int t = blockIdx.x * 256 + tid;
    float s = 0.0f;
    #pragma unroll 8
    for (int st = 0; st < 256; ++st) s += degp[(size_t)st * 24576 + t];
    if (t < 8192) deg[t] = s;
    else if (t < 16384) agg0[t - 8192] = s;
    else agg1[t - 16384] = s;
    if (blockIdx.x < 32) {               // these blocks cover deg exactly
        red[tid] = s;
        __syncthreads();
        for (int st = 128; st; st >>= 1) { if (tid < st) red[tid] += red[tid + st]; __syncthreads(); }
        if (tid == 0) atomicAdd(&scal[0], red[0]);
    }
}

__global__ __launch_bounds__(256) void k2_features(
    const float* __restrict__ nodes, const float* __restrict__ deg,
    const float* __restrict__ agg0, const float* __restrict__ agg1,
    const float* __restrict__ Wl1, const float* __restrict__ bl1, const float* __restrict__ Wr1,
    const float* __restrict__ Wl2, const float* __restrict__ bl2, const float* __restrict__ Wr2,
    float* __restrict__ x1, float* __restrict__ sm, float* __restrict__ scal) {
    const int lane = threadIdx.x & 63;
    const int node = blockIdx.x * 4 + (threadIdx.x >> 6);
    const float d = deg[node];
    const float inv = d > 0.0f ? 1.0f / d : 0.0f;
    const float a0 = agg0[node] * inv;
    const float a1 = agg1[node] * inv;
    const float n0 = nodes[2*node], n1 = nodes[2*node+1];
    float o1[2], o2[2];
    #pragma unroll
    for (int h = 0; h < 2; ++h) {
        const int c = lane + 64*h;
        o1[h] = a0*Wl1[2*c] + a1*Wl1[2*c+1] + bl1[c] + n0*Wr1[2*c] + n1*Wr1[2*c+1];
        o2[h] = a0*Wl2[2*c] + a1*Wl2[2*c+1] + bl2[c] + n0*Wr2[2*c] + n1*Wr2[2*c+1];
    }
    float ss1 = o1[0]*o1[0] + o1[1]*o1[1];
    float ss2 = o2[0]*o2[0] + o2[1]*o2[1];
    #pragma unroll
    for (int off = 32; off; off >>= 1) {
        ss1 += __shfl_xor(ss1, off);
        ss2 += __shfl_xor(ss2, off);
    }
    const float i1 = 1.0f / fmaxf(sqrtf(ss1), 1e-12f);
    const float i2 = 1.0f / fmaxf(sqrtf(ss2), 1e-12f);
    x1[(size_t)node*FF + lane]      = o1[0] * i1;
    x1[(size_t)node*FF + lane + 64] = o1[1] * i1;
    const float z0 = o2[0]*i2, z1 = o2[1]*i2;
    float mx = fmaxf(z0, z1);
    #pragma unroll
    for (int off = 32; off; off >>= 1) mx = fmaxf(mx, __shfl_xor(mx, off));
    const float e0 = expf(z0 - mx), e1 = expf(z1 - mx);
    float es = e0 + e1;
    #pragma unroll
    for (int off = 32; off; off >>= 1) es += __shfl_xor(es, off);
    const float isum = 1.0f / es;
    const float s0 = e0*isum, s1 = e1*isum;
    sm[(size_t)node*FF + lane]      = s0;
    sm[(size_t)node*FF + lane + 64] = s1;
    float ent = -s0*logf(s0 + 1e-15f) - s1*logf(s1 + 1e-15f);
    #pragma unroll
    for (int off = 32; off; off >>= 1) ent += __shfl_xor(ent, off);
    if (lane == 0) atomicAdd(&scal[2], ent);
}

// ---- LDS-blocked gather, direct bitmap walk -> t window-partials. ----
// block = (256-row i-strip) x (1024-col j-window); 512 threads; 64KB LDS.
__global__ __launch_bounds__(512) void kT3(
    const unsigned long long* __restrict__ bmp,
    const float* __restrict__ s, float* __restrict__ t_part) {
    __shared__ float sT[SUB][FF];      // 64 KB
    const int is  = blockIdx.x;        // 0..31
    const int jq  = blockIdx.y;        // 0..7
    const int r0  = is << 8;
    const int jlo0 = jq * JQ;
    const int tid = threadIdx.x;
    const int row = tid >> 1;          // 0..255 (local)
    const int half = tid & 1;
    const unsigned long long* __restrict__ wrow =
        bmp + ((size_t)(r0 + row) << 7) + (jq << 4);
    float4 acc[16] = {};               // 64 channels: half*64 .. +63
    for (int st = 0; st < JQ / SUB; ++st) {     // 8 subtiles of 128 cols
        const unsigned long long* wp = wrow + ((st >> 1) << 2);
        const int sh = (st & 1) << 5;
        const unsigned w32_0 = (unsigned)(wp[0] >> sh);
        const unsigned w32_1 = (unsigned)(wp[1] >> sh);
        const unsigned w32_2 = (unsigned)(wp[2] >> sh);
        const unsigned w32_3 = (unsigned)(wp[3] >> sh);
        __syncthreads();
        #pragma unroll
        for (int w = 0; w < (SUB * FF / 4) / 512; ++w) {   // 8 float4 per thread
            const int v  = tid + (w << 9);
            const int jr = v >> 5;
            const int c4 = v & 31;
            const float4 val = *reinterpret_cast<const float4*>(
                &s[(size_t)(jlo0 + (st << 7) + jr) * FF + (c4 << 2)]);
            *reinterpret_cast<float4*>(&sT[jr][(c4 ^ (jr & 7)) << 2]) = val;
        }
        __syncthreads();
        #pragma unroll
        for (int q = 0; q < 4; ++q) {
            unsigned w32 = (q == 0) ? w32_0 : (q == 1) ? w32_1 : (q == 2) ? w32_2 : w32_3;
            while (w32) {
                const int i = __ffs(w32) - 1;
                w32 &= w32 - 1u;
                const int jl = (i << 2) + q;
                #pragma unroll
                for (int qq = 0; qq < 16; ++qq) {
                    const int p = (half << 4) + qq;
                    const float4 sv = *reinterpret_cast<const float4*>(
                        &sT[jl][((p ^ (jl & 7)) << 2)]);
                    acc[qq].x += sv.x; acc[qq].y += sv.y; acc[qq].z += sv.z; acc[qq].w += sv.w;
                }
            }
        }
    }
    float* __restrict__ dst = t_part + ((size_t)jq << 20) +
                              ((size_t)(r0 + row) << 7) + (half << 6);
    #pragma unroll
    for (int qq = 0; qq < 16; ++qq)
        reinterpret_cast<float4*>(dst)[qq] = acc[qq];
}

// ---------------- fallback path (ws too small) ----------------
__global__ __launch_bounds__(256) void kA3_extract(
    const float* __restrict__ A, int* __restrict__ rowcnt, int* __restrict__ eidx,
    float* __restrict__ scal) {
    if (blockIdx.x == 0 && threadIdx.x < 16) scal[threadIdx.x] = 0.0f;
    const int lane = threadIdx.x & 63;
    const int row = blockIdx.x * 4 + (threadIdx.x >> 6);
    const float4* __restrict__ rp = reinterpret_cast<const float4*>(A + (size_t)row * NN);
    int* __restrict__ erow = eidx + (size_t)row * MAXD;
    int cnt = 0;
    const unsigned long long ltmask = (1ull << lane) - 1ull;
    for (int ch = 0; ch < 4; ++ch) {
        float4 v[8];
        #pragma unroll
        for (int k = 0; k < 8; ++k) v[k] = rp[(ch << 9) + (k << 6) + lane];
        #pragma unroll
        for (int k = 0; k < 8; ++k) {
            const float* f = reinterpret_cast<const float*>(&v[k]);
            #pragma unroll
            for (int q = 0; q < 4; ++q) {
                const bool hit = (f[q] != 0.0f);
                const unsigned long long m = __ballot(hit);
                if (hit) {
                    const int pos = cnt + __popcll(m & ltmask);
                    if (pos < MAXD)
                        erow[pos] = (((ch << 9) + (k << 6) + lane) << 2) + q;
                }
                cnt += (int)__popcll(m);
            }
        }
    }
    if (lane == 0) rowcnt[row] = min(cnt, MAXD);
}

__global__ __launch_bounds__(256) void kB_degagg(
    const int* __restrict__ rowcnt, const int* __restrict__ eidx,
    const float* __restrict__ nodes, float* __restrict__ deg,
    float* __restrict__ agg0, float* __restrict__ agg1) {
    const int lane = threadIdx.x & 63;
    const int row = blockIdx.x * 4 + (threadIdx.x >> 6);
    const int m = rowcnt[row];
    const float n0 = nodes[2*row], n1 = nodes[2*row+1];
    for (int k = lane; k < m; k += 64) {
        const int c = eidx[(size_t)row * MAXD + k];
        atomicAdd(&deg[c], 1.0f);
        atomicAdd(&agg0[c], n0);
        atomicAdd(&agg1[c], n1);
    }
}

__global__ __launch_bounds__(256) void k3_gather(
    const int* __restrict__ rowcnt, const int* __restrict__ eidx,
    const float* __restrict__ s, float* __restrict__ t, float* __restrict__ scal) {
    const int lane = threadIdx.x & 63;
    const int i = blockIdx.x * 4 + (threadIdx.x >> 6);
    const int m = rowcnt[i];
    int e0 = 0, e1 = 0;
    if (lane < m) e0 = eidx[(size_t)i * MAXD + lane];
    if (lane + 64 < m) e1 = eidx[(size_t)i * MAXD + lane + 64];
    float acc0 = 0.0f, acc1 = 0.0f;
    #pragma unroll 4
    for (int k = 0; k < m; ++k) {
        const int j = (k < 64) ? __shfl(e0, k) : __shfl(e1, k - 64);
        acc0 += s[(size_t)j * FF + lane];
        acc1 += s[(size_t)j * FF + lane + 64];
    }
    t[(size_t)i * FF + lane]      = acc0;
    t[(size_t)i * FF + lane + 64] = acc1;
    float dotp = acc0 * s[(size_t)i * FF + lane] + acc1 * s[(size_t)i * FF + lane + 64];
    #pragma unroll
    for (int off = 32; off; off >>= 1) dotp += __shfl_xor(dotp, off);
    if (lane == 0) {
        atomicAdd(&scal[1], dotp);
        atomicAdd(&scal[0], (float)m);
    }
}

// ---------------- shared tail ----------------
// PART==1: prod1 Q-staging sums NW t-partials; C written to cpart.
template <int PART>
__global__ __launch_bounds__(256) void k4_gemm(
    const float* __restrict__ sm, const float* __restrict__ x1,
    const float* __restrict__ t, float* __restrict__ C1,
    float* __restrict__ C2, float* __restrict__ G, float* __restrict__ cpart) {
    __shared__ float P[64][FF];
    __shared__ float Q[64][FF];
    const int prod = blockIdx.y;
    const float* __restrict__ Qsrc = (prod == 0) ? x1 : (prod == 1) ? t : sm;
    const int ta = (threadIdx.x >> 4) << 3;
    const int tb = (threadIdx.x & 15) << 3;
    float acc[8][8] = {};
    const int base = blockIdx.x * 128;
    for (int sub = 0; sub < 2; ++sub) {
        const int k0 = base + (sub << 6);
        __syncthreads();
        for (int l = threadIdx.x; l < 2048; l += 256) {
            const int rr = l >> 5;
            const int cc = (l & 31) << 2;
            *reinterpret_cast<float4*>(&P[rr][cc]) =
                *reinterpret_cast<const float4*>(&sm[(size_t)(k0+rr)*FF + cc]);
            float4 q;
            if (PART == 1 && prod == 1) {
                q = make_float4(0.f, 0.f, 0.f, 0.f);
                #pragma unroll
                for (int j = 0; j < NW; ++j) {
                    const float4 b = *reinterpret_cast<const float4*>(
                        &Qsrc[((size_t)j << 20) + (size_t)(k0+rr)*FF + cc]);
                    q.x += b.x; q.y += b.y; q.z += b.z; q.w += b.w;
                }
            } else {
                q = *reinterpret_cast<const float4*>(&Qsrc[(size_t)(k0+rr)*FF + cc]);
            }
            *reinterpret_cast<float4*>(&Q[rr][cc]) = q;
        }
        __syncthreads();
        for (int k = 0; k < 64; ++k) {
            float av[8], bv[8];
            *reinterpret_cast<float4*>(&av[0]) = *reinterpret_cast<const float4*>(&P[k][ta]);
            *reinterpret_cast<float4*>(&av[4]) = *reinterpret_cast<const float4*>(&P[k][ta+4]);
            *reinterpret_cast<float4*>(&bv[0]) = *reinterpret_cast<const float4*>(&Q[k][tb]);
            *reinterpret_cast<float4*>(&bv[4]) = *reinterpret_cast<const float4*>(&Q[k][tb+4]);
            #pragma unroll
            for (int a = 0; a < 8; ++a)
                #pragma unroll
                for (int b = 0; b < 8; ++b)
                    acc[a][b] = fmaf(av[a], bv[b], acc[a][b]);
        }
    }
    if (PART) {
        float* __restrict__ dst = cpart + ((size_t)prod * 64 + blockIdx.x) * 16384;
        #pragma unroll
        for (int a = 0; a < 8; ++a)
            #pragma unroll
            for (int b = 0; b < 8; ++b)
                dst[(ta+a)*FF + tb+b] = acc[a][b];
    } else {
        float* __restrict__ Cdst = (prod == 0) ? C1 : (prod == 1) ? C2 : G;
        #pragma unroll
        for (int a = 0; a < 8; ++a)
            #pragma unroll
            for (int b = 0; b < 8; ++b)
                atomicAdd(&Cdst[(ta+a)*FF + tb+b], acc[a][b]);
    }
}

// sum 64 K-slice partials; fused post: adj_p copy/zero-count, G^2, linkdot=trace(C2)
__global__ __launch_bounds__(256) void k4r_reduce(
    const float* __restrict__ cpart, float* __restrict__ C1,
    float* __restrict__ C2, float* __restrict__ G,
    float* __restrict__ out, float* __restrict__ scal) {
    __shared__ float red[256];
    const int tid = threadIdx.x;
    const int e = blockIdx.x * 256 + tid;
    const int prod = blockIdx.y;
    const float* __restrict__ p = cpart + (size_t)prod * 64 * 16384 + e;
    float sum = 0.0f;
    #pragma unroll
    for (int k = 0; k < 64; ++k) sum += p[(size_t)k * 16384];
    float* __restrict__ dst = (prod == 0) ? C1 : (prod == 1) ? C2 : G;
    dst[e] = sum;
    if (prod == 1) {
        out[260 + e] = sum;
        if ((e >> 7) == (e & 127)) atomicAdd(&scal[1], sum);   // linkdot = trace(C2)
        red[tid] = (sum == 0.0f) ? 1.0f : 0.0f;
        __syncthreads();
        for (int st = 128; st; st >>= 1) { if (tid < st) red[tid] += red[tid + st]; __syncthreads(); }
        if (tid == 0) atomicAdd(&scal[4], red[0]);
    } else if (prod == 2) {
        red[tid] = sum * sum;
        __syncthreads();
        for (int st = 128; st; st >>= 1) { if (tid < st) red[tid] += red[tid + st]; __syncthreads(); }
        if (tid == 0) atomicAdd(&scal[3], red[0]);
    }
}

__global__ __launch_bounds__(256) void k4b_post(
    const float* __restrict__ C2, const float* __restrict__ G,
    float* __restrict__ out, float* __restrict__ scal) {
    __shared__ float red[256];
    const int tid = threadIdx.x;
    const int e = blockIdx.x * 256 + tid;
    const float v = C2[e];
    out[260 + e] = v;
    const float g = G[e];
    red[tid] = (v == 0.0f) ? 1.0f : 0.0f;
    __syncthreads();
    for (int st = 128; st; st >>= 1) { if (tid < st) red[tid] += red[tid + st]; __syncthreads(); }
    if (tid == 0) atomicAdd(&scal[4], red[0]);
    __syncthreads();
    red[tid] = g * g;
    __syncthreads();
    for (int st = 128; st; st >>= 1) { if (tid < st) red[tid] += red[tid + st]; __syncthreads(); }
    if (tid == 0) atomicAdd(&scal[3], red[0]);
}

__global__ __launch_bounds__(128) void k5b_agg3(
    const float* __restrict__ C2, const float* __restrict__ C1,
    float* __restrict__ agg3n) {
    const int c = blockIdx.x;
    const int f = threadIdx.x;
    float sum = 0.0f, dg = 0.0f;
    for (int j = 0; j < 128; ++j) {
        const float a = C2[j*FF + c];
        if (a != 0.0f) { sum += C1[j*FF + f]; dg += 1.0f; }
    }
    agg3n[c*FF + f] = (dg > 0.0f) ? sum / dg : 0.0f;
}

__global__ __launch_bounds__(128) void k5c_final(
    const float* __restrict__ agg3n, const float* __restrict__ C1,
    const float* __restrict__ Wl3, const float* __restrict__ bl3,
    const float* __restrict__ Wr3, const float* __restrict__ scal,
    float* __restrict__ out) {
    __shared__ float red[256];
    const int r = threadIdx.x;
    float o[2];
    #pragma unroll
    for (int k = 0; k < 2; ++k) {
        float acc = bl3[k];
        for (int f = 0; f < 128; ++f)
            acc += agg3n[r*FF + f] * Wl3[k*FF + f] + C1[r*FF + f] * Wr3[k*FF + f];
        o[k] = acc;
    }
    const float nrm = sqrtf(o[0]*o[0] + o[1]*o[1]);
    const float inv = 1.0f / fmaxf(nrm, 1e-12f);
    const float xs0 = o[0]*inv, xs1 = o[1]*inv;
    out[4 + 2*r]     = tanhf(xs0);
    out[4 + 2*r + 1] = tanhf(xs1);
    red[r] = xs0;
    red[128 + r] = xs1;
    __syncthreads();
    for (int st = 64; st; st >>= 1) {
        if (r < st) { red[r] += red[r + st]; red[128 + r] += red[128 + r + st]; }
        __syncthreads();
    }
    if (r == 0) {
        out[0] = red[0];
        out[1] = red[128];
        const float nnz = scal[0], dot = scal[1], ent = scal[2], gsq = scal[3], zc = scal[4];
        const float l1sq = nnz - 2.0f*dot + gsq;
        const float link1 = sqrtf(fmaxf(l1sq, 0.0f)) / 67108864.0f;
        const float link2 = sqrtf(zc) / 16384.0f;
        out[2] = link1 + link2;
        out[3] = ent / 8192.0f;
    }
}

extern "C" void kernel_launch(void* const* d_in, const int* in_sizes, int n_in,
                              void* d_out, int out_size, void* d_ws, size_t ws_size,
                              hipStream_t stream) {
    const float* nodes = (const float*)d_in[0];
    const float* A     = (const float*)d_in[1];
    const float* Wl1   = (const float*)d_in[2];
    const float* bl1   = (const float*)d_in[3];
    const float* Wr1   = (const float*)d_in[4];
    const float* Wl2   = (const float*)d_in[5];
    const float* bl2   = (const float*)d_in[6];
    const float* Wr2   = (const float*)d_in[7];
    const float* Wl3   = (const float*)d_in[8];
    const float* bl3   = (const float*)d_in[9];
    const float* Wr3   = (const float*)d_in[10];
    float* out = (float*)d_out;
    float* ws  = (float*)d_ws;

    float* deg    = ws + OFF_DEG;
    float* agg0   = ws + OFF_AGG;
    float* agg1   = ws + OFF_AGG + 8192;
    float* C1     = ws + OFF_C1;
    float* C2     = ws + OFF_C2;
    float* G      = ws + OFF_G;
    float* scal   = ws + OFF_SCAL;
    int*   rowcnt = (int*)(ws + OFF_RCNT);
    float* x1     = ws + OFF_X1;
    float* sbuf   = ws + OFF_S;
    float* agg3n  = ws + OFF_A3;
    float* part   = ws + OFF_PART;

    const bool use_part = (ws_size >= NEED_PART_BYTES);

    if (use_part) {
        unsigned long long* bmpW = (unsigned long long*)(ws + OFF_T);
        float* tpart = part;                 // 8 x 1M floats (kSF2 degp reuses this)
        float* cpart = part + CPART_OFF;     // 3 x 1M floats

        kSF2<<<1024, 256, 0, stream>>>(A, nodes, bmpW, tpart, scal);
        kB2r<<<96, 256, 0, stream>>>(tpart, deg, agg0, agg1, scal);
        k2_features<<<2048, 256, 0, stream>>>(nodes, deg, agg0, agg1,
                                              Wl1, bl1, Wr1, Wl2, bl2, Wr2,
                                              x1, sbuf, scal);
        kT3<<<dim3(32, NW), 512, 0, stream>>>(bmpW, sbuf, tpart);
        k4_gemm<1><<<dim3(64, 3), 256, 0, stream>>>(sbuf, x1, tpart, C1, C2, G, cpart);
        k4r_reduce<<<dim3(64, 3), 256, 0, stream>>>(cpart, C1, C2, G, out, scal);
    } else {
        float* tbuf = ws + OFF_T;
        int*   eidx = (int*)(ws + OFF_EIDX);
        k0_zero<<<(ZN + 255) / 256, 256, 0, stream>>>(ws, ZN);
        kA3_extract<<<2048, 256, 0, stream>>>(A, rowcnt, eidx, scal);
        kB_degagg<<<2048, 256, 0, stream>>>(rowcnt, eidx, nodes, deg, agg0, agg1);
        k2_features<<<2048, 256, 0, stream>>>(nodes, deg, agg0, agg1,
                                              Wl1, bl1, Wr1, Wl2, bl2, Wr2,
                                              x1, sbuf, scal);
        k3_gather<<<2048, 256, 0, stream>>>(rowcnt, eidx, sbuf, tbuf, scal);
        k4_gemm<0><<<dim3(64, 3), 256, 0, stream>>>(sbuf, x1, tbuf, C1, C2, G, part);
        k4b_post<<<64, 256, 0, stream>>>(C2, G, out, scal);
    }
    k5b_agg3<<<128, 128, 0, stream>>>(C2, C1, agg3n);
    k5c_final<<<1, 128, 0, stream>>>(agg3n, C1, Wl3, bl3, Wr3, scal, out);
}

// Round 18
// 352.521 us; speedup vs baseline: 1.0596x; 1.0596x over previous
//
#include <hip/hip_runtime.h>
#include <math.h>

#define NN 8192
#define FF 128
#define MAXD 128
#define JQ 1024      // columns per j-window
#define NW 8         // number of j-windows
#define SUB 128      // s rows staged per subtile (kT3)

// ---------------- workspace layout (float offsets) ----------------
static constexpr int OFF_DEG  = 0;          // 8192
static constexpr int OFF_AGG  = 8192;       // 16384: agg0[8192], agg1[8192]
static constexpr int OFF_C1   = 24576;      // 16384  x_pool = s^T x1
static constexpr int OFF_C2   = 40960;      // 16384  adj_p  = s^T t
static constexpr int OFF_G    = 57344;      // 16384  G = s^T s
static constexpr int OFF_SCAL = 73728;      // 16
static constexpr int OFF_RCNT = 73744;      // 8192 (int)  [fallback only]
static constexpr int ZN       = 81936;
// non-zeroed:
static constexpr int OFF_X1   = 81936;      // 8192*128
static constexpr int OFF_S    = 1130512;    // 8192*128
static constexpr int OFF_T    = 2179088;    // main: BITMAP (8 MB spans T+EIDX); fallback: t
static constexpr int OFF_EIDX = 3227664;    // fallback: eidx
static constexpr int OFF_A3   = 4276240;    // 16384
static constexpr int OFF_PART = 4292624;    // tpart (8x1M; kB3 degp reuses) ++ cpart (3x1M)
static constexpr int CPART_OFF = 8388608;   // cpart offset within part
static constexpr size_t NEED_PART_BYTES =
    (size_t)(OFF_PART + CPART_OFF + 3*1048576) * 4;

__global__ __launch_bounds__(256) void k0_zero(float* __restrict__ p, int n) {
    int i = blockIdx.x * 256 + threadIdx.x;
    if (i < n) p[i] = 0.0f;
}

// ---- Pure coalesced scan: A -> ballot bitmap. ----
// Block = one row; wave wv covers cols [wv*2048,+2048) in 8 chunks of 256.
// word[row*128 + chunk*4 + q], bit l <-> col chunk*256 + l*4 + q.
__global__ __launch_bounds__(256) void kScan(
    const float* __restrict__ A, unsigned long long* __restrict__ bmp,
    float* __restrict__ scal) {
    if (blockIdx.x == 0 && threadIdx.x < 16) scal[threadIdx.x] = 0.0f;
    const int row  = blockIdx.x;
    const int lane = threadIdx.x & 63;
    const int wv   = threadIdx.x >> 6;
    const float* __restrict__ base = A + (size_t)row * NN + (wv << 11);
    float4 v[8];
    #pragma unroll
    for (int c = 0; c < 8; ++c)
        v[c] = *reinterpret_cast<const float4*>(base + (c << 8) + (lane << 2));
    unsigned long long* __restrict__ wp = bmp + ((size_t)row << 7) + (wv << 5);
    #pragma unroll
    for (int c = 0; c < 8; ++c) {
        const unsigned long long m0 = __ballot(v[c].x != 0.0f);
        const unsigned long long m1 = __ballot(v[c].y != 0.0f);
        const unsigned long long m2 = __ballot(v[c].z != 0.0f);
        const unsigned long long m3 = __ballot(v[c].w != 0.0f);
        if (lane == 0) {
            wp[(c << 2) + 0] = m0; wp[(c << 2) + 1] = m1;
            wp[(c << 2) + 2] = m2; wp[(c << 2) + 3] = m3;
        }
    }
}

// ---- deg/agg from ballot bitmap via LDS histograms. ----
// block = (128-row strip) x (2048-col quarter); 256 blocks; 24KB LDS.
__global__ __launch_bounds__(256) void kB3(
    const unsigned long long* __restrict__ bmp, const float* __restrict__ nodes,
    float* __restrict__ degp) {
    __shared__ float hd[2048], h0[2048], h1[2048];
    const int strip = blockIdx.x >> 2;   // 0..63 (128 rows)
    const int q4    = blockIdx.x & 3;    // 0..3  (2048 cols)
    const int tid = threadIdx.x;
    for (int i = tid; i < 2048; i += 256) { hd[i] = 0.0f; h0[i] = 0.0f; h1[i] = 0.0f; }
    __syncthreads();
    const int row = (strip << 7) + (tid >> 1);
    const int half = tid & 1;
    const float n0 = nodes[2*row], n1 = nodes[2*row+1];
    const unsigned long long* __restrict__ wp =
        bmp + ((size_t)row << 7) + (q4 << 5) + (half << 4);
    #pragma unroll 4
    for (int k = 0; k < 16; ++k) {
        unsigned long long w = wp[k];
        while (w) {
            const int b = __ffsll(w) - 1;
            w &= w - 1ull;
            const int rel = (half << 10) + ((k >> 2) << 8) + (b << 2) + (k & 3);
            atomicAdd(&hd[rel], 1.0f);
            atomicAdd(&h0[rel], n0);
            atomicAdd(&h1[rel], n1);
        }
    }
    __syncthreads();
    float* __restrict__ dstp = degp + (size_t)strip * 24576 + (q4 << 11);
    for (int i = tid; i < 2048; i += 256) {
        dstp[i]         = hd[i];
        dstp[8192 + i]  = h0[i];
        dstp[16384 + i] = h1[i];
    }
}

// reduce 64 strip-partials -> deg, agg0, agg1 ; nnz = sum(deg) -> scal[0]
__global__ __launch_bounds__(256) void kB2r(
    const float* __restrict__ degp, float* __restrict__ deg,
    float* __restrict__ agg0, float* __restrict__ agg1,
    float* __restrict__ scal) {
    __shared__ float red[256];
    const int tid = threadIdx.x;
    const int t = blockIdx.x * 256 + tid;
    float s = 0.0f;
    #pragma unroll 8
    for (int st = 0; st < 64; ++st) s += degp[(size_t)st * 24576 + t];
    if (t < 8192) deg[t] = s;
    else if (t < 16384) agg0[t - 8192] = s;
    else agg1[t - 16384] = s;
    if (blockIdx.x < 32) {               // these blocks cover deg exactly
        red[tid] = s;
        __syncthreads();
        for (int st = 128; st; st >>= 1) { if (tid < st) red[tid] += red[tid + st]; __syncthreads(); }
        if (tid == 0) atomicAdd(&scal[0], red[0]);
    }
}

__global__ __launch_bounds__(256) void k2_features(
    const float* __restrict__ nodes, const float* __restrict__ deg,
    const float* __restrict__ agg0, const float* __restrict__ agg1,
    const float* __restrict__ Wl1, const float* __restrict__ bl1, const float* __restrict__ Wr1,
    const float* __restrict__ Wl2, const float* __restrict__ bl2, const float* __restrict__ Wr2,
    float* __restrict__ x1, float* __restrict__ sm, float* __restrict__ scal) {
    const int lane = threadIdx.x & 63;
    const int node = blockIdx.x * 4 + (threadIdx.x >> 6);
    const float d = deg[node];
    const float inv = d > 0.0f ? 1.0f / d : 0.0f;
    const float a0 = agg0[node] * inv;
    const float a1 = agg1[node] * inv;
    const float n0 = nodes[2*node], n1 = nodes[2*node+1];
    float o1[2], o2[2];
    #pragma unroll
    for (int h = 0; h < 2; ++h) {
        const int c = lane + 64*h;
        o1[h] = a0*Wl1[2*c] + a1*Wl1[2*c+1] + bl1[c] + n0*Wr1[2*c] + n1*Wr1[2*c+1];
        o2[h] = a0*Wl2[2*c] + a1*Wl2[2*c+1] + bl2[c] + n0*Wr2[2*c] + n1*Wr2[2*c+1];
    }
    float ss1 = o1[0]*o1[0] + o1[1]*o1[1];
    float ss2 = o2[0]*o2[0] + o2[1]*o2[1];
    #pragma unroll
    for (int off = 32; off; off >>= 1) {
        ss1 += __shfl_xor(ss1, off);
        ss2 += __shfl_xor(ss2, off);
    }
    const float i1 = 1.0f / fmaxf(sqrtf(ss1), 1e-12f);
    const float i2 = 1.0f / fmaxf(sqrtf(ss2), 1e-12f);
    x1[(size_t)node*FF + lane]      = o1[0] * i1;
    x1[(size_t)node*FF + lane + 64] = o1[1] * i1;
    const float z0 = o2[0]*i2, z1 = o2[1]*i2;
    float mx = fmaxf(z0, z1);
    #pragma unroll
    for (int off = 32; off; off >>= 1) mx = fmaxf(mx, __shfl_xor(mx, off));
    const float e0 = expf(z0 - mx), e1 = expf(z1 - mx);
    float es = e0 + e1;
    #pragma unroll
    for (int off = 32; off; off >>= 1) es += __shfl_xor(es, off);
    const float isum = 1.0f / es;
    const float s0 = e0*isum, s1 = e1*isum;
    sm[(size_t)node*FF + lane]      = s0;
    sm[(size_t)node*FF + lane + 64] = s1;
    float ent = -s0*logf(s0 + 1e-15f) - s1*logf(s1 + 1e-15f);
    #pragma unroll
    for (int off = 32; off; off >>= 1) ent += __shfl_xor(ent, off);
    if (lane == 0) atomicAdd(&scal[2], ent);
}

// ---- LDS-blocked gather, direct bitmap walk -> t window-partials. ----
// block = (256-row i-strip) x (1024-col j-window); 512 threads; 64KB LDS.
__global__ __launch_bounds__(512) void kT3(
    const unsigned long long* __restrict__ bmp,
    const float* __restrict__ s, float* __restrict__ t_part) {
    __shared__ float sT[SUB][FF];      // 64 KB
    const int is  = blockIdx.x;        // 0..31
    const int jq  = blockIdx.y;        // 0..7
    const int r0  = is << 8;
    const int jlo0 = jq * JQ;
    const int tid = threadIdx.x;
    const int row = tid >> 1;          // 0..255 (local)
    const int half = tid & 1;
    const unsigned long long* __restrict__ wrow =
        bmp + ((size_t)(r0 + row) << 7) + (jq << 4);
    float4 acc[16] = {};               // 64 channels: half*64 .. +63
    for (int st = 0; st < JQ / SUB; ++st) {     // 8 subtiles of 128 cols
        const unsigned long long* wp = wrow + ((st >> 1) << 2);
        const int sh = (st & 1) << 5;
        const unsigned w32_0 = (unsigned)(wp[0] >> sh);
        const unsigned w32_1 = (unsigned)(wp[1] >> sh);
        const unsigned w32_2 = (unsigned)(wp[2] >> sh);
        const unsigned w32_3 = (unsigned)(wp[3] >> sh);
        __syncthreads();
        #pragma unroll
        for (int w = 0; w < (SUB * FF / 4) / 512; ++w) {   // 8 float4 per thread
            const int v  = tid + (w << 9);
            const int jr = v >> 5;
            const int c4 = v & 31;
            const float4 val = *reinterpret_cast<const float4*>(
                &s[(size_t)(jlo0 + (st << 7) + jr) * FF + (c4 << 2)]);
            *reinterpret_cast<float4*>(&sT[jr][(c4 ^ (jr & 7)) << 2]) = val;
        }
        __syncthreads();
        #pragma unroll
        for (int q = 0; q < 4; ++q) {
            unsigned w32 = (q == 0) ? w32_0 : (q == 1) ? w32_1 : (q == 2) ? w32_2 : w32_3;
            while (w32) {
                const int i = __ffs(w32) - 1;
                w32 &= w32 - 1u;
                const int jl = (i << 2) + q;
                #pragma unroll
                for (int qq = 0; qq < 16; ++qq) {
                    const int p = (half << 4) + qq;
                    const float4 sv = *reinterpret_cast<const float4*>(
                        &sT[jl][((p ^ (jl & 7)) << 2)]);
                    acc[qq].x += sv.x; acc[qq].y += sv.y; acc[qq].z += sv.z; acc[qq].w += sv.w;
                }
            }
        }
    }
    float* __restrict__ dst = t_part + ((size_t)jq << 20) +
                              ((size_t)(r0 + row) << 7) + (half << 6);
    #pragma unroll
    for (int qq = 0; qq < 16; ++qq)
        reinterpret_cast<float4*>(dst)[qq] = acc[qq];
}

// ---------------- fallback path (ws too small) ----------------
__global__ __launch_bounds__(256) void kA3_extract(
    const float* __restrict__ A, int* __restrict__ rowcnt, int* __restrict__ eidx,
    float* __restrict__ scal) {
    if (blockIdx.x == 0 && threadIdx.x < 16) scal[threadIdx.x] = 0.0f;
    const int lane = threadIdx.x & 63;
    const int row = blockIdx.x * 4 + (threadIdx.x >> 6);
    const float4* __restrict__ rp = reinterpret_cast<const float4*>(A + (size_t)row * NN);
    int* __restrict__ erow = eidx + (size_t)row * MAXD;
    int cnt = 0;
    const unsigned long long ltmask = (1ull << lane) - 1ull;
    for (int ch = 0; ch < 4; ++ch) {
        float4 v[8];
        #pragma unroll
        for (int k = 0; k < 8; ++k) v[k] = rp[(ch << 9) + (k << 6) + lane];
        #pragma unroll
        for (int k = 0; k < 8; ++k) {
            const float* f = reinterpret_cast<const float*>(&v[k]);
            #pragma unroll
            for (int q = 0; q < 4; ++q) {
                const bool hit = (f[q] != 0.0f);
                const unsigned long long m = __ballot(hit);
                if (hit) {
                    const int pos = cnt + __popcll(m & ltmask);
                    if (pos < MAXD)
                        erow[pos] = (((ch << 9) + (k << 6) + lane) << 2) + q;
                }
                cnt += (int)__popcll(m);
            }
        }
    }
    if (lane == 0) rowcnt[row] = min(cnt, MAXD);
}

__global__ __launch_bounds__(256) void kB_degagg(
    const int* __restrict__ rowcnt, const int* __restrict__ eidx,
    const float* __restrict__ nodes, float* __restrict__ deg,
    float* __restrict__ agg0, float* __restrict__ agg1) {
    const int lane = threadIdx.x & 63;
    const int row = blockIdx.x * 4 + (threadIdx.x >> 6);
    const int m = rowcnt[row];
    const float n0 = nodes[2*row], n1 = nodes[2*row+1];
    for (int k = lane; k < m; k += 64) {
        const int c = eidx[(size_t)row * MAXD + k];
        atomicAdd(&deg[c], 1.0f);
        atomicAdd(&agg0[c], n0);
        atomicAdd(&agg1[c], n1);
    }
}

__global__ __launch_bounds__(256) void k3_gather(
    const int* __restrict__ rowcnt, const int* __restrict__ eidx,
    const float* __restrict__ s, float* __restrict__ t, float* __restrict__ scal) {
    const int lane = threadIdx.x & 63;
    const int i = blockIdx.x * 4 + (threadIdx.x >> 6);
    const int m = rowcnt[i];
    int e0 = 0, e1 = 0;
    if (lane < m) e0 = eidx[(size_t)i * MAXD + lane];
    if (lane + 64 < m) e1 = eidx[(size_t)i * MAXD + lane + 64];
    float acc0 = 0.0f, acc1 = 0.0f;
    #pragma unroll 4
    for (int k = 0; k < m; ++k) {
        const int j = (k < 64) ? __shfl(e0, k) : __shfl(e1, k - 64);
        acc0 += s[(size_t)j * FF + lane];
        acc1 += s[(size_t)j * FF + lane + 64];
    }
    t[(size_t)i * FF + lane]      = acc0;
    t[(size_t)i * FF + lane + 64] = acc1;
    float dotp = acc0 * s[(size_t)i * FF + lane] + acc1 * s[(size_t)i * FF + lane + 64];
    #pragma unroll
    for (int off = 32; off; off >>= 1) dotp += __shfl_xor(dotp, off);
    if (lane == 0) {
        atomicAdd(&scal[1], dotp);
        atomicAdd(&scal[0], (float)m);
    }
}

// ---------------- shared tail ----------------
// PART==1: prod1 Q-staging sums NW t-partials; C written to cpart.
template <int PART>
__global__ __launch_bounds__(256) void k4_gemm(
    const float* __restrict__ sm, const float* __restrict__ x1,
    const float* __restrict__ t, float* __restrict__ C1,
    float* __restrict__ C2, float* __restrict__ G, float* __restrict__ cpart) {
    __shared__ float P[64][FF];
    __shared__ float Q[64][FF];
    const int prod = blockIdx.y;
    const float* __restrict__ Qsrc = (prod == 0) ? x1 : (prod == 1) ? t : sm;
    const int ta = (threadIdx.x >> 4) << 3;
    const int tb = (threadIdx.x & 15) << 3;
    float acc[8][8] = {};
    const int base = blockIdx.x * 128;
    for (int sub = 0; sub < 2; ++sub) {
        const int k0 = base + (sub << 6);
        __syncthreads();
        for (int l = threadIdx.x; l < 2048; l += 256) {
            const int rr = l >> 5;
            const int cc = (l & 31) << 2;
            *reinterpret_cast<float4*>(&P[rr][cc]) =
                *reinterpret_cast<const float4*>(&sm[(size_t)(k0+rr)*FF + cc]);
            float4 q;
            if (PART == 1 && prod == 1) {
                q = make_float4(0.f, 0.f, 0.f, 0.f);
                #pragma unroll
                for (int j = 0; j < NW; ++j) {
                    const float4 b = *reinterpret_cast<const float4*>(
                        &Qsrc[((size_t)j << 20) + (size_t)(k0+rr)*FF + cc]);
                    q.x += b.x; q.y += b.y; q.z += b.z; q.w += b.w;
                }
            } else {
                q = *reinterpret_cast<const float4*>(&Qsrc[(size_t)(k0+rr)*FF + cc]);
            }
            *reinterpret_cast<float4*>(&Q[rr][cc]) = q;
        }
        __syncthreads();
        for (int k = 0; k < 64; ++k) {
            float av[8], bv[8];
            *reinterpret_cast<float4*>(&av[0]) = *reinterpret_cast<const float4*>(&P[k][ta]);
            *reinterpret_cast<float4*>(&av[4]) = *reinterpret_cast<const float4*>(&P[k][ta+4]);
            *reinterpret_cast<float4*>(&bv[0]) = *reinterpret_cast<const float4*>(&Q[k][tb]);
            *reinterpret_cast<float4*>(&bv[4]) = *reinterpret_cast<const float4*>(&Q[k][tb+4]);
            #pragma unroll
            for (int a = 0; a < 8; ++a)
                #pragma unroll
                for (int b = 0; b < 8; ++b)
                    acc[a][b] = fmaf(av[a], bv[b], acc[a][b]);
        }
    }
    if (PART) {
        float* __restrict__ dst = cpart + ((size_t)prod * 64 + blockIdx.x) * 16384;
        #pragma unroll
        for (int a = 0; a < 8; ++a)
            #pragma unroll
            for (int b = 0; b < 8; ++b)
                dst[(ta+a)*FF + tb+b] = acc[a][b];
    } else {
        float* __restrict__ Cdst = (prod == 0) ? C1 : (prod == 1) ? C2 : G;
        #pragma unroll
        for (int a = 0; a < 8; ++a)
            #pragma unroll
            for (int b = 0; b < 8; ++b)
                atomicAdd(&Cdst[(ta+a)*FF + tb+b], acc[a][b]);
    }
}

// sum 64 K-slice partials; fused post: adj_p copy/zero-count, G^2, linkdot=trace(C2)
__global__ __launch_bounds__(256) void k4r_reduce(
    const float* __restrict__ cpart, float* __restrict__ C1,
    float* __restrict__ C2, float* __restrict__ G,
    float* __restrict__ out, float* __restrict__ scal) {
    __shared__ float red[256];
    const int tid = threadIdx.x;
    const int e = blockIdx.x * 256 + tid;
    const int prod = blockIdx.y;
    const float* __restrict__ p = cpart + (size_t)prod * 64 * 16384 + e;
    float sum = 0.0f;
    #pragma unroll
    for (int k = 0; k < 64; ++k) sum += p[(size_t)k * 16384];
    float* __restrict__ dst = (prod == 0) ? C1 : (prod == 1) ? C2 : G;
    dst[e] = sum;
    if (prod == 1) {
        out[260 + e] = sum;
        if ((e >> 7) == (e & 127)) atomicAdd(&scal[1], sum);   // linkdot = trace(C2)
        red[tid] = (sum == 0.0f) ? 1.0f : 0.0f;
        __syncthreads();
        for (int st = 128; st; st >>= 1) { if (tid < st) red[tid] += red[tid + st]; __syncthreads(); }
        if (tid == 0) atomicAdd(&scal[4], red[0]);
    } else if (prod == 2) {
        red[tid] = sum * sum;
        __syncthreads();
        for (int st = 128; st; st >>= 1) { if (tid < st) red[tid] += red[tid + st]; __syncthreads(); }
        if (tid == 0) atomicAdd(&scal[3], red[0]);
    }
}

__global__ __launch_bounds__(256) void k4b_post(
    const float* __restrict__ C2, const float* __restrict__ G,
    float* __restrict__ out, float* __restrict__ scal) {
    __shared__ float red[256];
    const int tid = threadIdx.x;
    const int e = blockIdx.x * 256 + tid;
    const float v = C2[e];
    out[260 + e] = v;
    const float g = G[e];
    red[tid] = (v == 0.0f) ? 1.0f : 0.0f;
    __syncthreads();
    for (int st = 128; st; st >>= 1) { if (tid < st) red[tid] += red[tid + st]; __syncthreads(); }
    if (tid == 0) atomicAdd(&scal[4], red[0]);
    __syncthreads();
    red[tid] = g * g;
    __syncthreads();
    for (int st = 128; st; st >>= 1) { if (tid < st) red[tid] += red[tid + st]; __syncthreads(); }
    if (tid == 0) atomicAdd(&scal[3], red[0]);
}

__global__ __launch_bounds__(128) void k5b_agg3(
    const float* __restrict__ C2, const float* __restrict__ C1,
    float* __restrict__ agg3n) {
    const int c = blockIdx.x;
    const int f = threadIdx.x;
    float sum = 0.0f, dg = 0.0f;
    for (int j = 0; j < 128; ++j) {
        const float a = C2[j*FF + c];
        if (a != 0.0f) { sum += C1[j*FF + f]; dg += 1.0f; }
    }
    agg3n[c*FF + f] = (dg > 0.0f) ? sum / dg : 0.0f;
}

__global__ __launch_bounds__(128) void k5c_final(
    const float* __restrict__ agg3n, const float* __restrict__ C1,
    const float* __restrict__ Wl3, const float* __restrict__ bl3,
    const float* __restrict__ Wr3, const float* __restrict__ scal,
    float* __restrict__ out) {
    __shared__ float red[256];
    const int r = threadIdx.x;
    float o[2];
    #pragma unroll
    for (int k = 0; k < 2; ++k) {
        float acc = bl3[k];
        for (int f = 0; f < 128; ++f)
            acc += agg3n[r*FF + f] * Wl3[k*FF + f] + C1[r*FF + f] * Wr3[k*FF + f];
        o[k] = acc;
    }
    const float nrm = sqrtf(o[0]*o[0] + o[1]*o[1]);
    const float inv = 1.0f / fmaxf(nrm, 1e-12f);
    const float xs0 = o[0]*inv, xs1 = o[1]*inv;
    out[4 + 2*r]     = tanhf(xs0);
    out[4 + 2*r + 1] = tanhf(xs1);
    red[r] = xs0;
    red[128 + r] = xs1;
    __syncthreads();
    for (int st = 64; st; st >>= 1) {
        if (r < st) { red[r] += red[r + st]; red[128 + r] += red[128 + r + st]; }
        __syncthreads();
    }
    if (r == 0) {
        out[0] = red[0];
        out[1] = red[128];
        const float nnz = scal[0], dot = scal[1], ent = scal[2], gsq = scal[3], zc = scal[4];
        const float l1sq = nnz - 2.0f*dot + gsq;
        const float link1 = sqrtf(fmaxf(l1sq, 0.0f)) / 67108864.0f;
        const float link2 = sqrtf(zc) / 16384.0f;
        out[2] = link1 + link2;
        out[3] = ent / 8192.0f;
    }
}

extern "C" void kernel_launch(void* const* d_in, const int* in_sizes, int n_in,
                              void* d_out, int out_size, void* d_ws, size_t ws_size,
                              hipStream_t stream) {
    const float* nodes = (const float*)d_in[0];
    const float* A     = (const float*)d_in[1];
    const float* Wl1   = (const float*)d_in[2];
    const float* bl1   = (const float*)d_in[3];
    const float* Wr1   = (const float*)d_in[4];
    const float* Wl2   = (const float*)d_in[5];
    const float* bl2   = (const float*)d_in[6];
    const float* Wr2   = (const float*)d_in[7];
    const float* Wl3   = (const float*)d_in[8];
    const float* bl3   = (const float*)d_in[9];
    const float* Wr3   = (const float*)d_in[10];
    float* out = (float*)d_out;
    float* ws  = (float*)d_ws;

    float* deg    = ws + OFF_DEG;
    float* agg0   = ws + OFF_AGG;
    float* agg1   = ws + OFF_AGG + 8192;
    float* C1     = ws + OFF_C1;
    float* C2     = ws + OFF_C2;
    float* G      = ws + OFF_G;
    float* scal   = ws + OFF_SCAL;
    int*   rowcnt = (int*)(ws + OFF_RCNT);
    float* x1     = ws + OFF_X1;
    float* sbuf   = ws + OFF_S;
    float* agg3n  = ws + OFF_A3;
    float* part   = ws + OFF_PART;

    const bool use_part = (ws_size >= NEED_PART_BYTES);

    if (use_part) {
        unsigned long long* bmpW = (unsigned long long*)(ws + OFF_T);
        float* tpart = part;                 // 8 x 1M floats (kB3 degp reuses)
        float* cpart = part + CPART_OFF;     // 3 x 1M floats

        kScan<<<NN, 256, 0, stream>>>(A, bmpW, scal);
        kB3<<<256, 256, 0, stream>>>(bmpW, nodes, tpart);
        kB2r<<<96, 256, 0, stream>>>(tpart, deg, agg0, agg1, scal);
        k2_features<<<2048, 256, 0, stream>>>(nodes, deg, agg0, agg1,
                                              Wl1, bl1, Wr1, Wl2, bl2, Wr2,
                                              x1, sbuf, scal);
        kT3<<<dim3(32, NW), 512, 0, stream>>>(bmpW, sbuf, tpart);
        k4_gemm<1><<<dim3(64, 3), 256, 0, stream>>>(sbuf, x1, tpart, C1, C2, G, cpart);
        k4r_reduce<<<dim3(64, 3), 256, 0, stream>>>(cpart, C1, C2, G, out, scal);
    } else {
        float* tbuf = ws + OFF_T;
        int*   eidx = (int*)(ws + OFF_EIDX);
        k0_zero<<<(ZN + 255) / 256, 256, 0, stream>>>(ws, ZN);
        kA3_extract<<<2048, 256, 0, stream>>>(A, rowcnt, eidx, scal);
        kB_degagg<<<2048, 256, 0, stream>>>(rowcnt, eidx, nodes, deg, agg0, agg1);
        k2_features<<<2048, 256, 0, stream>>>(nodes, deg, agg0, agg1,
                                              Wl1, bl1, Wr1, Wl2, bl2, Wr2,
                                              x1, sbuf, scal);
        k3_gather<<<2048, 256, 0, stream>>>(rowcnt, eidx, sbuf, tbuf, scal);
        k4_gemm<0><<<dim3(64, 3), 256, 0, stream>>>(sbuf, x1, tbuf, C1, C2, G, part);
        k4b_post<<<64, 256, 0, stream>>>(C2, G, out, scal);
    }
    k5b_agg3<<<128, 128, 0, stream>>>(C2, C1, agg3n);
    k5c_final<<<1, 128, 0, stream>>>(agg3n, C1, Wl3, bl3, Wr3, scal, out);
}